// Round 1
// baseline (759.826 us; speedup 1.0000x reference)
//
#include <hip/hip_runtime.h>
#include <hip/hip_bf16.h>
#include <math.h>

// Problem constants
#define BATCH 8
#define LTOT 4096
#define DEMB 1024
#define NH 16
#define DH 64

// K1/K3 tiling: 32 chunks per batch, 128 rows per chunk, 512 threads.
#define CHUNKS 32
#define ROWS_PER_BLOCK (LTOT / CHUNKS)   // 128
#define TL 32                             // rows per tile (phase A covers 32 rows w/ 512 thr)

// ws layout (floats):
//   S      [B][1024][16]  @ 0        (131072)
//   sv     [B][16]        @ 131072   (128)
//   wq_eff [B][1024][16]  @ 131200   (131072)   (i-major, h contiguous)
//   c      [B][16]        @ 262272   (128)
#define WS_S   0
#define WS_SV  131072
#define WS_WQ  131200
#define WS_C   262272

// ---------------------------------------------------------------------------
// K1: compute v rows on the fly, accumulate S[b,i,h] = sum_l x[b,l,i]*v[b,l,h]
//     and sv[b,h] = sum_l v[b,l,h].  One block = (batch b, 128-row chunk).
// ---------------------------------------------------------------------------
__global__ __launch_bounds__(512) void k1_v_outer(
    const float* __restrict__ x, const float* __restrict__ Wv,
    const float* __restrict__ bv, float* __restrict__ S, float* __restrict__ sv) {
  __shared__ float wv_lds[DEMB * NH];   // 64 KB
  __shared__ float v_tile[TL * NH];     // 2 KB
  __shared__ float sv_red[512];         // 2 KB

  const int b = blockIdx.x >> 5;
  const int chunk = blockIdx.x & 31;
  const int l0 = chunk * ROWS_PER_BLOCK;
  const int t = threadIdx.x;

  // stage Wv (64 KB) into LDS, coalesced float4
  for (int j = t * 4; j < DEMB * NH; j += 512 * 4)
    *(float4*)&wv_lds[j] = *(const float4*)&Wv[j];
  __syncthreads();

  const int r = t >> 4;   // 0..31 : local row for phase A
  const int h = t & 15;   // head
  const float bvh = bv[h];

  float acc0[16], acc1[16];
  #pragma unroll
  for (int hh = 0; hh < 16; ++hh) { acc0[hh] = 0.f; acc1[hh] = 0.f; }
  float sv_acc = 0.f;

  const float* xb = x + (size_t)b * LTOT * DEMB;

  for (int tile = 0; tile < ROWS_PER_BLOCK / TL; ++tile) {
    const int lbase = l0 + tile * TL;

    // ---- phase A: v for TL=32 rows; thread (r,h) computes v[lbase+r, h]
    {
      const float* xrow = xb + (size_t)(lbase + r) * DEMB;
      float v = bvh;
      #pragma unroll 4
      for (int i = 0; i < DEMB; i += 4) {
        const float4 x4 = *(const float4*)&xrow[i];
        v += x4.x * wv_lds[(i + 0) * NH + h];
        v += x4.y * wv_lds[(i + 1) * NH + h];
        v += x4.z * wv_lds[(i + 2) * NH + h];
        v += x4.w * wv_lds[(i + 3) * NH + h];
      }
      v_tile[r * NH + h] = v;
      sv_acc += v;
    }
    __syncthreads();

    // ---- phase B: S accumulate. thread owns i = t and i = t+512, all 16 h.
    #pragma unroll 4
    for (int l = 0; l < TL; ++l) {
      const float* xrow = xb + (size_t)(lbase + l) * DEMB;
      const float xv0 = xrow[t];
      const float xv1 = xrow[t + 512];
      #pragma unroll
      for (int hh = 0; hh < 16; ++hh) {
        const float vl = v_tile[l * NH + hh];   // broadcast
        acc0[hh] += xv0 * vl;
        acc1[hh] += xv1 * vl;
      }
    }
    __syncthreads();
  }

  // write partial S (32 chunks per batch collide -> atomics)
  float* Sb = S + (size_t)b * DEMB * NH;
  #pragma unroll
  for (int hh = 0; hh < 16; ++hh) atomicAdd(&Sb[t * NH + hh], acc0[hh]);
  #pragma unroll
  for (int hh = 0; hh < 16; ++hh) atomicAdd(&Sb[(t + 512) * NH + hh], acc1[hh]);

  // sv reduction within block, then one atomic per head
  sv_red[t] = sv_acc;
  __syncthreads();
  if (t < 16) {
    float s = 0.f;
    #pragma unroll
    for (int r2 = 0; r2 < 32; ++r2) s += sv_red[r2 * 16 + t];
    atomicAdd(&sv[b * NH + t], s);
  }
}

// ---------------------------------------------------------------------------
// K2: per (b,h): ktv[d] = sum_i Wk[i, h*64+d]*S[b,i,h] + bk[h*64+d]*sv[b,h]
//     then wq_eff[b,i,h] = sum_d Wq[i, h*64+d]*ktv[d]; c[b,h] = bq_h . ktv
// ---------------------------------------------------------------------------
__global__ __launch_bounds__(256) void k2_ktv_wq(
    const float* __restrict__ Wq, const float* __restrict__ bq,
    const float* __restrict__ Wk, const float* __restrict__ bk,
    const float* __restrict__ S, const float* __restrict__ sv,
    float* __restrict__ wq_eff, float* __restrict__ cvec) {
  __shared__ float ktv_part[4][DH];
  __shared__ float ktv[DH];
  const int b = blockIdx.x >> 4;
  const int h = blockIdx.x & 15;
  const int t = threadIdx.x;
  const float* Sb = S + (size_t)b * DEMB * NH;

  const int d = t & 63, seg = t >> 6;
  float p = 0.f;
  for (int i = seg * 256; i < seg * 256 + 256; ++i)
    p += Wk[(size_t)i * DEMB + h * DH + d] * Sb[i * NH + h];
  ktv_part[seg][d] = p;
  __syncthreads();
  if (t < 64) {
    float s = ktv_part[0][t] + ktv_part[1][t] + ktv_part[2][t] + ktv_part[3][t];
    s += bk[h * DH + t] * sv[b * NH + h];
    ktv[t] = s;
  }
  __syncthreads();

  float* wq_b = wq_eff + (size_t)b * DEMB * NH;
  #pragma unroll
  for (int k = 0; k < 4; ++k) {
    const int i = t + 256 * k;
    const float* wrow = &Wq[(size_t)i * DEMB + h * DH];
    float s = 0.f;
    #pragma unroll
    for (int dd = 0; dd < DH; dd += 4) {
      const float4 w4 = *(const float4*)&wrow[dd];
      s += w4.x * ktv[dd] + w4.y * ktv[dd + 1] + w4.z * ktv[dd + 2] + w4.w * ktv[dd + 3];
    }
    wq_b[i * NH + h] = s;
  }
  if (t == 0) {
    float s = 0.f;
    for (int dd = 0; dd < DH; ++dd) s += bq[h * DH + dd] * ktv[dd];
    cvec[b * NH + h] = s;
  }
}

// ---------------------------------------------------------------------------
// K3: z[b,h,l] = (x[b,l] . wq_eff[b,h] + c[b,h]) / 8 ; out = sigmoid(z)*mask
// ---------------------------------------------------------------------------
__global__ __launch_bounds__(512) void k3_z_sigmoid(
    const float* __restrict__ x, const int* __restrict__ mask,
    const float* __restrict__ wq_eff, const float* __restrict__ cvec,
    float* __restrict__ out) {
  __shared__ float wq_lds[DEMB * NH];   // 64 KB
  __shared__ float c_lds[NH];

  const int b = blockIdx.x >> 5;
  const int chunk = blockIdx.x & 31;
  const int l0 = chunk * ROWS_PER_BLOCK;
  const int t = threadIdx.x;

  const float* wq_b = wq_eff + (size_t)b * DEMB * NH;
  for (int j = t * 4; j < DEMB * NH; j += 512 * 4)
    *(float4*)&wq_lds[j] = *(const float4*)&wq_b[j];
  if (t < 16) c_lds[t] = cvec[b * NH + t];
  __syncthreads();

  const int r = t >> 4;   // 0..31
  const int h = t & 15;
  const float c = c_lds[h];
  const float* xb = x + (size_t)b * LTOT * DEMB;

  for (int tile = 0; tile < ROWS_PER_BLOCK / TL; ++tile) {
    const int l = l0 + tile * TL + r;
    const float* xrow = xb + (size_t)l * DEMB;
    float z = c;
    #pragma unroll 4
    for (int i = 0; i < DEMB; i += 4) {
      const float4 x4 = *(const float4*)&xrow[i];
      z += x4.x * wq_lds[(i + 0) * NH + h];
      z += x4.y * wq_lds[(i + 1) * NH + h];
      z += x4.z * wq_lds[(i + 2) * NH + h];
      z += x4.w * wq_lds[(i + 3) * NH + h];
    }
    z *= 0.125f;  // 1/sqrt(64)
    float pr = 1.f / (1.f + __expf(-z));
    if (mask[b * LTOT + l] == 0) pr = 0.f;
    out[((size_t)(b * NH + h)) * LTOT + l] = pr;
  }
}

extern "C" void kernel_launch(void* const* d_in, const int* in_sizes, int n_in,
                              void* d_out, int out_size, void* d_ws, size_t ws_size,
                              hipStream_t stream) {
  const float* x  = (const float*)d_in[0];
  const int*  mask = (const int*)d_in[1];
  const float* Wq = (const float*)d_in[2];
  const float* bq = (const float*)d_in[3];
  const float* Wk = (const float*)d_in[4];
  const float* bk = (const float*)d_in[5];
  const float* Wv = (const float*)d_in[6];
  const float* bv = (const float*)d_in[7];
  float* out = (float*)d_out;
  float* ws = (float*)d_ws;

  float* S      = ws + WS_S;
  float* sv     = ws + WS_SV;
  float* wq_eff = ws + WS_WQ;
  float* cvec   = ws + WS_C;

  // zero the accumulated regions (ws is poisoned 0xAA before every launch)
  hipMemsetAsync(S, 0, (size_t)(WS_SV + 128 - WS_S) * sizeof(float), stream);

  k1_v_outer<<<dim3(BATCH * CHUNKS), dim3(512), 0, stream>>>(x, Wv, bv, S, sv);
  k2_ktv_wq<<<dim3(BATCH * NH), dim3(256), 0, stream>>>(Wq, bq, Wk, bk, S, sv, wq_eff, cvec);
  k3_z_sigmoid<<<dim3(BATCH * CHUNKS), dim3(512), 0, stream>>>(x, mask, wq_eff, cvec, out);
}

// Round 2
// 380.496 us; speedup vs baseline: 1.9969x; 1.9969x over previous
//
#include <hip/hip_runtime.h>
#include <hip/hip_bf16.h>
#include <math.h>

// Problem constants
#define BATCH 8
#define LTOT 4096
#define DEMB 1024
#define NH 16
#define DH 64

#define CHUNKS 32                       // l-chunks per batch
#define ROWS_PER_BLOCK (LTOT / CHUNKS)  // 128
#define TILE 64                         // rows per pipeline tile
#define NTILES (ROWS_PER_BLOCK / TILE)  // 2

// ws layout (floats):
//   S      [B][1024][16]      @ 0        (131072)   (reduced)
//   sv     [B][16]            @ 131072   (128)
//   wq_eff [B][1024][16]      @ 131200   (131072)
//   c      [B][16]            @ 262272   (128)
//   Spart  [B*32][1024][16]   @ 262400   (4194304)  (per-block partials)
#define WS_S     0
#define WS_SV    131072
#define WS_WQ    131200
#define WS_C     262272
#define WS_SPART 262400
#define WS_NEED  ((size_t)(WS_SPART + BATCH * CHUNKS * DEMB * NH) * 4)

// dot of one x-row (global, broadcast-cached) with LDS matrix column h,
// 4 independent accumulator chains for ILP.
__device__ __forceinline__ float dot_row_lds(const float* __restrict__ xrow,
                                             const float* __restrict__ w, int h) {
  float a0 = 0.f, a1 = 0.f, a2 = 0.f, a3 = 0.f;
  #pragma unroll 4
  for (int i = 0; i < DEMB; i += 16) {
    const float4 p0 = *(const float4*)&xrow[i + 0];
    const float4 p1 = *(const float4*)&xrow[i + 4];
    const float4 p2 = *(const float4*)&xrow[i + 8];
    const float4 p3 = *(const float4*)&xrow[i + 12];
    a0 += p0.x * w[(i + 0) * NH + h] + p0.y * w[(i + 1) * NH + h]
        + p0.z * w[(i + 2) * NH + h] + p0.w * w[(i + 3) * NH + h];
    a1 += p1.x * w[(i + 4) * NH + h] + p1.y * w[(i + 5) * NH + h]
        + p1.z * w[(i + 6) * NH + h] + p1.w * w[(i + 7) * NH + h];
    a2 += p2.x * w[(i + 8) * NH + h] + p2.y * w[(i + 9) * NH + h]
        + p2.z * w[(i + 10) * NH + h] + p2.w * w[(i + 11) * NH + h];
    a3 += p3.x * w[(i + 12) * NH + h] + p3.y * w[(i + 13) * NH + h]
        + p3.z * w[(i + 14) * NH + h] + p3.w * w[(i + 15) * NH + h];
  }
  return (a0 + a1) + (a2 + a3);
}

// ---------------------------------------------------------------------------
// K1: fused v + S. 1024 threads. Software-pipelined:
//   A(tile): thread (r=t>>4, h=t&15) computes v[row,h] (4-chain dot)
//   B(tile): thread t owns column i=t, acc[16] += x[l,t]*v[l,h]
// One barrier per tile; v double-buffered.
// ---------------------------------------------------------------------------
__global__ __launch_bounds__(1024) void k1_fused(
    const float* __restrict__ x, const float* __restrict__ Wv,
    const float* __restrict__ bv, float* __restrict__ Spart,
    float* __restrict__ S, float* __restrict__ sv, int direct) {
  __shared__ float wv_lds[DEMB * NH];       // 64 KB
  __shared__ float vt[2][TILE * NH];        // 8 KB
  __shared__ float sv_red[1024];            // 4 KB

  const int b = blockIdx.x >> 5;
  const int chunk = blockIdx.x & 31;
  const int l0 = chunk * ROWS_PER_BLOCK;
  const int t = threadIdx.x;

  // stage Wv (64 KB), coalesced float4: 1024 thr x 4 float4
  #pragma unroll
  for (int j = t * 4; j < DEMB * NH; j += 1024 * 4)
    *(float4*)&wv_lds[j] = *(const float4*)&Wv[j];
  __syncthreads();

  const int r = t >> 4;    // 0..63
  const int h = t & 15;
  const float bvh = bv[h];
  const float* xb = x + (size_t)b * LTOT * DEMB;

  float acc[16];
  #pragma unroll
  for (int hh = 0; hh < 16; ++hh) acc[hh] = 0.f;
  float sv_acc = 0.f;

  // prologue: A(tile 0)
  {
    const float v = bvh + dot_row_lds(xb + (size_t)(l0 + r) * DEMB, wv_lds, h);
    vt[0][r * NH + h] = v;
    sv_acc += v;
  }

  for (int tile = 0; tile < NTILES; ++tile) {
    __syncthreads();
    // A(tile+1) into the other buffer (overlaps with B(tile))
    if (tile + 1 < NTILES) {
      const float v = bvh +
          dot_row_lds(xb + (size_t)(l0 + (tile + 1) * TILE + r) * DEMB, wv_lds, h);
      vt[(tile + 1) & 1][r * NH + h] = v;
      sv_acc += v;
    }
    // B(tile): column accumulate from vt[tile&1]
    const float* vbuf = vt[tile & 1];
    const int lbase = l0 + tile * TILE;
    #pragma unroll 4
    for (int l = 0; l < TILE; ++l) {
      const float xv = xb[(size_t)(lbase + l) * DEMB + t];
      const float4 v0 = *(const float4*)&vbuf[l * NH + 0];
      const float4 v1 = *(const float4*)&vbuf[l * NH + 4];
      const float4 v2 = *(const float4*)&vbuf[l * NH + 8];
      const float4 v3 = *(const float4*)&vbuf[l * NH + 12];
      acc[0] += xv * v0.x;  acc[1] += xv * v0.y;  acc[2] += xv * v0.z;  acc[3] += xv * v0.w;
      acc[4] += xv * v1.x;  acc[5] += xv * v1.y;  acc[6] += xv * v1.z;  acc[7] += xv * v1.w;
      acc[8] += xv * v2.x;  acc[9] += xv * v2.y;  acc[10] += xv * v2.z; acc[11] += xv * v2.w;
      acc[12] += xv * v3.x; acc[13] += xv * v3.y; acc[14] += xv * v3.z; acc[15] += xv * v3.w;
    }
  }

  // write S partials: direct per-block buffer (no atomics) or atomic fallback
  if (direct) {
    float* dst = Spart + ((size_t)blockIdx.x << 14) + t * NH;
    *(float4*)&dst[0]  = make_float4(acc[0], acc[1], acc[2], acc[3]);
    *(float4*)&dst[4]  = make_float4(acc[4], acc[5], acc[6], acc[7]);
    *(float4*)&dst[8]  = make_float4(acc[8], acc[9], acc[10], acc[11]);
    *(float4*)&dst[12] = make_float4(acc[12], acc[13], acc[14], acc[15]);
  } else {
    float* Sb = S + ((size_t)b << 14);
    #pragma unroll
    for (int hh = 0; hh < 16; ++hh) atomicAdd(&Sb[t * NH + hh], acc[hh]);
  }

  // sv reduction: one atomic per (b,h)
  sv_red[t] = sv_acc;
  __syncthreads();
  if (t < 16) {
    float s = 0.f;
    #pragma unroll
    for (int rr = 0; rr < 64; ++rr) s += sv_red[rr * 16 + t];
    atomicAdd(&sv[b * NH + t], s);
  }
}

// ---------------------------------------------------------------------------
// K1b: reduce 32 chunk-partials -> S.  grid B*16, 256 thr, 4 outputs/thread.
// ---------------------------------------------------------------------------
__global__ __launch_bounds__(256) void k1b_reduce(
    const float* __restrict__ Spart, float* __restrict__ S) {
  const int b = blockIdx.x >> 4;
  const int seg = blockIdx.x & 15;
  #pragma unroll
  for (int k = 0; k < 4; ++k) {
    const int idx = seg * 1024 + k * 256 + threadIdx.x;
    float s = 0.f;
    #pragma unroll 8
    for (int c = 0; c < CHUNKS; ++c)
      s += Spart[((size_t)(b * CHUNKS + c) << 14) + idx];
    S[((size_t)b << 14) + idx] = s;
  }
}

// ---------------------------------------------------------------------------
// K2: ktv + wq_eff + c. grid B*NH, 1024 thr.
// ---------------------------------------------------------------------------
__global__ __launch_bounds__(1024) void k2_ktv_wq(
    const float* __restrict__ Wq, const float* __restrict__ bq,
    const float* __restrict__ Wk, const float* __restrict__ bk,
    const float* __restrict__ S, const float* __restrict__ sv,
    float* __restrict__ wq_eff, float* __restrict__ cvec) {
  __shared__ float part[16][DH];
  __shared__ float ktv[DH];
  const int b = blockIdx.x >> 4;
  const int h = blockIdx.x & 15;
  const int t = threadIdx.x;
  const float* Sb = S + ((size_t)b << 14);

  const int d = t & 63, seg = t >> 6;   // 16 segs x 64 i each
  float p = 0.f;
  #pragma unroll 4
  for (int i = seg * 64; i < seg * 64 + 64; ++i)
    p += Wk[(size_t)i * DEMB + h * DH + d] * Sb[i * NH + h];
  part[seg][d] = p;
  __syncthreads();
  if (t < 64) {
    float s = 0.f;
    #pragma unroll
    for (int k = 0; k < 16; ++k) s += part[k][t];
    s += bk[h * DH + t] * sv[b * NH + h];
    ktv[t] = s;
  }
  __syncthreads();

  // wq_eff: one row i per thread
  {
    const int i = t;
    const float* wrow = &Wq[(size_t)i * DEMB + h * DH];
    float s0 = 0.f, s1 = 0.f;
    #pragma unroll
    for (int dd = 0; dd < DH; dd += 8) {
      const float4 w4 = *(const float4*)&wrow[dd];
      const float4 w5 = *(const float4*)&wrow[dd + 4];
      s0 += w4.x * ktv[dd] + w4.y * ktv[dd + 1] + w4.z * ktv[dd + 2] + w4.w * ktv[dd + 3];
      s1 += w5.x * ktv[dd + 4] + w5.y * ktv[dd + 5] + w5.z * ktv[dd + 6] + w5.w * ktv[dd + 7];
    }
    wq_eff[((size_t)b << 14) + i * NH + h] = s0 + s1;
  }
  if (t == 0) {
    float s = 0.f;
    for (int dd = 0; dd < DH; ++dd) s += bq[h * DH + dd] * ktv[dd];
    cvec[b * NH + h] = s;
  }
}

// ---------------------------------------------------------------------------
// K3: z = (x . wq_eff + c)/8 -> sigmoid -> mask. 1024 thr, 2 rows/thread.
// ---------------------------------------------------------------------------
__global__ __launch_bounds__(1024) void k3_z_sigmoid(
    const float* __restrict__ x, const int* __restrict__ mask,
    const float* __restrict__ wq_eff, const float* __restrict__ cvec,
    float* __restrict__ out) {
  __shared__ float wq_lds[DEMB * NH];   // 64 KB
  __shared__ float c_lds[NH];

  const int b = blockIdx.x >> 5;
  const int chunk = blockIdx.x & 31;
  const int l0 = chunk * ROWS_PER_BLOCK;
  const int t = threadIdx.x;

  const float* wq_b = wq_eff + ((size_t)b << 14);
  #pragma unroll
  for (int j = t * 4; j < DEMB * NH; j += 1024 * 4)
    *(float4*)&wq_lds[j] = *(const float4*)&wq_b[j];
  if (t < 16) c_lds[t] = cvec[b * NH + t];
  __syncthreads();

  const int r = t >> 4;
  const int h = t & 15;
  const float c = c_lds[h];
  const float* xb = x + (size_t)b * LTOT * DEMB;

  #pragma unroll
  for (int tile = 0; tile < NTILES; ++tile) {
    const int l = l0 + tile * TILE + r;
    float z = c + dot_row_lds(xb + (size_t)l * DEMB, wq_lds, h);
    z *= 0.125f;  // 1/sqrt(64)
    float pr = 1.f / (1.f + __expf(-z));
    if (mask[b * LTOT + l] == 0) pr = 0.f;
    out[((size_t)(b * NH + h)) * LTOT + l] = pr;
  }
}

extern "C" void kernel_launch(void* const* d_in, const int* in_sizes, int n_in,
                              void* d_out, int out_size, void* d_ws, size_t ws_size,
                              hipStream_t stream) {
  const float* x  = (const float*)d_in[0];
  const int* mask = (const int*)d_in[1];
  const float* Wq = (const float*)d_in[2];
  const float* bq = (const float*)d_in[3];
  const float* Wk = (const float*)d_in[4];
  const float* bk = (const float*)d_in[5];
  const float* Wv = (const float*)d_in[6];
  const float* bv = (const float*)d_in[7];
  float* out = (float*)d_out;
  float* ws = (float*)d_ws;

  float* S      = ws + WS_S;
  float* sv     = ws + WS_SV;
  float* wq_eff = ws + WS_WQ;
  float* cvec   = ws + WS_C;
  float* Spart  = ws + WS_SPART;

  const int direct = (ws_size >= WS_NEED) ? 1 : 0;

  // sv is atomically accumulated -> zero it. S too if using atomic fallback.
  hipMemsetAsync(sv, 0, 128 * sizeof(float), stream);
  if (!direct) hipMemsetAsync(S, 0, (size_t)BATCH * DEMB * NH * sizeof(float), stream);

  k1_fused<<<dim3(BATCH * CHUNKS), dim3(1024), 0, stream>>>(x, Wv, bv, Spart, S, sv, direct);
  if (direct)
    k1b_reduce<<<dim3(BATCH * 16), dim3(256), 0, stream>>>(Spart, S);
  k2_ktv_wq<<<dim3(BATCH * NH), dim3(1024), 0, stream>>>(Wq, bq, Wk, bk, S, sv, wq_eff, cvec);
  k3_z_sigmoid<<<dim3(BATCH * CHUNKS), dim3(1024), 0, stream>>>(x, mask, wq_eff, cvec, out);
}